// Round 7
// baseline (408.450 us; speedup 1.0000x reference)
//
#include <hip/hip_runtime.h>
#include <hip/hip_fp16.h>

// ImageReconstruction: unfold -> soft-VQ softmax(35*(2ab - b2)) over 256 codes
// -> sparse reconstruct -> fold, + choice penalty (sum min(w,1-w) / N).
//
// Round-8: round-7's split was right but wrote 25MB at fixed offsets into d_ws
// without checking ws_size -> OOB corruption (absmax 1.0 = stray w values).
// Fix: K1 stashes each patch's sparse (w, code) list INSIDE the patch's own
// 256B output region (pairs in rows 0-5, count in row 6); K2 reads the stash
// and overwrites it with the reconstruction. Zero workspace beyond the
// validated 65KB. LDS pair = 1 word (f16 delta + 8b code; delta in [-13.8,0],
// RNE err <= 0.4% rel on w -> absmax ~0.008 < 0.02) -> NSLOT 24, LDS 39168B,
// 4 blocks/CU at (256,4). Dominant code always stored (delta=0 -> e=1 > TAU).
//  * K1: A-load + B DMA dbuf + merged GEMM + online softmax (validated r5),
//    append (f16(s-m_half), code) on e>TAU via wave-local LDS atomicAdd;
//    flush w = exp(delta + (half0 ? m_h0 - m_final : 0)) * invS. Penalty
//    closed-form. No rr[16], no blk loads, no recon staging in K1.
//  * K2: per patch <=24 broadcast pairs, rr[d=lane] = sum w*blk[c][d];
//    patches independent -> ILP; no MFMA -> (256,8) high occupancy;
//    68-stride LDS transpose + float4 writeout overwrites the stash.

typedef short short8 __attribute__((ext_vector_type(8)));
typedef float floatx4 __attribute__((ext_vector_type(4)));

namespace {
constexpr float BETA_C = 35.0f;
constexpr float TAU    = 1e-6f;
constexpr float INV_N  = 1.0f / 262144.0f;
constexpr size_t IMG_ELEMS = (size_t)64 * 512 * 512;
constexpr int NSLOT = 24;      // pairs per patch (clamped; P(overflow) ~ 1e-12)
// K1 LDS words: B dbuf + packed pair lists + counts.
constexpr int WB0 = 0;         // Bh of current half: [0, 4096)
constexpr int WB1 = 4096;      // Bl of current half: [4096, 8192)
constexpr int WP  = 8192;      // pairs: 64 patches x 24 words -> [8192, 9728)
constexpr int WC  = 9728;      // counts: 64 words -> [9728, 9792)
constexpr int NWORDS = 9792;   // 39168 B -> 4 blocks/CU
}

__device__ __forceinline__ unsigned short f2bf(float x) {  // round-to-nearest
  unsigned u = __float_as_uint(x);
  return (unsigned short)((u + 0x7FFFu + ((u >> 16) & 1u)) >> 16);
}
__device__ __forceinline__ float bf2f(unsigned short h) {
  return __uint_as_float((unsigned)h << 16);
}
__device__ __forceinline__ unsigned pack2(unsigned short lo, unsigned short hi) {
  return (unsigned)lo | ((unsigned)hi << 16);
}
// A-split: hi = RNE bf16, lo = TRUNCATED bf16 of residual (err <= 2^-17 * a).
__device__ __forceinline__ void cvt8t(float4 a, float4 b, short8& h, short8& l) {
  float f[8] = {a.x, a.y, a.z, a.w, b.x, b.y, b.z, b.w};
#pragma unroll
  for (int i = 0; i < 8; ++i) {
    unsigned short hh = f2bf(f[i]);
    h[i] = (short)hh;
    float lf = f[i] - bf2f(hh);
    l[i] = (short)(__float_as_uint(lf) >> 16);
  }
}
// Async 16B global -> LDS (wave-uniform LDS base + lane*16; per-lane gsrc).
__device__ __forceinline__ void cp16(const uint4* g, unsigned* l) {
  __builtin_amdgcn_global_load_lds(
      (const __attribute__((address_space(1))) void*)g,
      (__attribute__((address_space(3))) void*)l, 16, 0, 0);
}

// Pre-kernel: split codebook into bf16 hi/lo granules, stored PRE-SWIZZLED
// (code c, granule g -> slot c*8 + (g ^ (c&7))), + per-code -BETA*||b||^2.
__global__ void pack_codes(const float* __restrict__ blk,
                           unsigned* __restrict__ wsBh,
                           unsigned* __restrict__ wsBl,
                           float* __restrict__ wsB2) {
  const int gid = blockIdx.x * 256 + threadIdx.x;   // 0..2047
  const int c = gid >> 3, g = gid & 7;
  const float* src = blk + c * 64 + g * 8;
  float4 a = *reinterpret_cast<const float4*>(src);
  float4 b = *reinterpret_cast<const float4*>(src + 4);
  float f[8] = {a.x, a.y, a.z, a.w, b.x, b.y, b.z, b.w};
  uint4 ph, pl;
  unsigned* phw = reinterpret_cast<unsigned*>(&ph);
  unsigned* plw = reinterpret_cast<unsigned*>(&pl);
  float b2 = 0.f;
#pragma unroll
  for (int t = 0; t < 4; ++t) {
    float v0 = f[2 * t], v1 = f[2 * t + 1];
    b2 += v0 * v0 + v1 * v1;
    unsigned short h0 = f2bf(v0), h1 = f2bf(v1);
    unsigned short l0 = f2bf(v0 - bf2f(h0)), l1 = f2bf(v1 - bf2f(h1));
    phw[t] = pack2(h0, h1);
    plw[t] = pack2(l0, l1);
  }
  const int slot = c * 8 + (g ^ (c & 7));
  reinterpret_cast<uint4*>(wsBh)[slot] = ph;
  reinterpret_cast<uint4*>(wsBl)[slot] = pl;
  b2 += __shfl_xor(b2, 1, 64);
  b2 += __shfl_xor(b2, 2, 64);
  b2 += __shfl_xor(b2, 4, 64);
  if (g == 0) wsB2[c] = -BETA_C * b2;
}

__global__ __launch_bounds__(256, 4) void recon_kernel(
    const float* __restrict__ img,
    const unsigned* __restrict__ wsBh, const unsigned* __restrict__ wsBl,
    const float* __restrict__ wsB2,
    float* __restrict__ out, float* __restrict__ penAcc) {
  __shared__ unsigned sMem[NWORDS];

  const int tid = threadIdx.x;
  const int lane = tid & 63;
  const int wave = tid >> 6;
  const int b = blockIdx.x >> 6;
  const int ht = blockIdx.x & 63;
  const int c15 = lane & 15;
  const int q = lane >> 4;

  // zero this wave's pair counts (wave-local region; same-wave LDS ordering)
  if (lane < 16) sMem[WC + wave * 16 + lane] = 0;

  // ---- A fragments direct from HBM (issue first, convert later) ----
  const float* imgBase = img + (size_t)b * (512 * 512) + (size_t)(ht * 8) * 512;
  const float* aptr = imgBase + q * 512 + (wave * 16 + c15) * 8;
  float4 v00 = *reinterpret_cast<const float4*>(aptr);
  float4 v01 = *reinterpret_cast<const float4*>(aptr + 4);
  float4 v10 = *reinterpret_cast<const float4*>(aptr + 2048);       // row q+4
  float4 v11 = *reinterpret_cast<const float4*>(aptr + 2048 + 4);

  // ---- issue half-0 stages: Bh -> buf0, Bl -> buf1 (async DMA) ----
  const uint4* srcH = reinterpret_cast<const uint4*>(wsBh);
  const uint4* srcL = reinterpret_cast<const uint4*>(wsBl);
#pragma unroll
  for (int i = 0; i < 4; ++i) {
    cp16(srcH + i * 256 + tid, &sMem[WB0 + (i * 4 + wave) * 256]);
    cp16(srcL + i * 256 + tid, &sMem[WB1 + (i * 4 + wave) * 256]);
  }

  // ---- convert A to bf16 hi/lo fragments (overlaps DMA flight) ----
  short8 ah[2], al[2];
  cvt8t(v00, v01, ah[0], al[0]);   // k = 8q..8q+7
  cvt8t(v10, v11, ah[1], al[1]);   // k = 32+8q..39+8q

  asm volatile("s_waitcnt vmcnt(0)" ::: "memory");
  __syncthreads();  // bar1: half-0 B staged

  // B-frag addresses: in-half code cl = 16n+c15, granules q and q^4,
  // swizzle key cl&7 == c15&7 (pre-swizzled at pack time).
  const int kx = c15 & 7;
  const unsigned* pb0 = &sMem[(8 * c15 + (q ^ kx)) * 4];
  const unsigned* pb1 = &sMem[(8 * c15 + ((q ^ 4) ^ kx)) * 4];

  float m[4], mOld[4], sm[4];

#pragma unroll
  for (int h = 0; h < 2; ++h) {
    floatx4 acc[8];
#pragma unroll
    for (int n = 0; n < 8; ++n) acc[n] = (floatx4){0.f, 0.f, 0.f, 0.f};
    // ---- merged GEMM: (Ah+Al)*Bh + Ah*Bl, 48 mfma ----
#pragma unroll
    for (int n = 0; n < 8; ++n) {
      short8 b0h = *reinterpret_cast<const short8*>(pb0 + 512 * n);
      short8 b1h = *reinterpret_cast<const short8*>(pb1 + 512 * n);
      short8 b0l = *reinterpret_cast<const short8*>(pb0 + WB1 + 512 * n);
      short8 b1l = *reinterpret_cast<const short8*>(pb1 + WB1 + 512 * n);
      acc[n] = __builtin_amdgcn_mfma_f32_16x16x32_bf16(ah[0], b0h, acc[n], 0, 0, 0);
      acc[n] = __builtin_amdgcn_mfma_f32_16x16x32_bf16(al[0], b0h, acc[n], 0, 0, 0);
      acc[n] = __builtin_amdgcn_mfma_f32_16x16x32_bf16(ah[1], b1h, acc[n], 0, 0, 0);
      acc[n] = __builtin_amdgcn_mfma_f32_16x16x32_bf16(al[1], b1h, acc[n], 0, 0, 0);
      acc[n] = __builtin_amdgcn_mfma_f32_16x16x32_bf16(ah[0], b0l, acc[n], 0, 0, 0);
      acc[n] = __builtin_amdgcn_mfma_f32_16x16x32_bf16(ah[1], b1l, acc[n], 0, 0, 0);
    }
    if (h == 0) {
      __syncthreads();  // bar2: all half-0 B reads done
      // issue half-1 stages; flight hides under the epilogue below
#pragma unroll
      for (int i = 0; i < 4; ++i) {
        cp16(srcH + 1024 + i * 256 + tid, &sMem[WB0 + (i * 4 + wave) * 256]);
        cp16(srcL + 1024 + i * 256 + tid, &sMem[WB1 + (i * 4 + wave) * 256]);
      }
    }

    // ---- logits (col=c15 -> code 128h+16n+c15, row=4q+r -> patch) ----
#pragma unroll
    for (int n = 0; n < 8; ++n) {
      float b2s = wsB2[128 * h + 16 * n + c15];   // == -BETA*||b||^2
#pragma unroll
      for (int r = 0; r < 4; ++r)
        acc[n][r] = fmaf(2.0f * BETA_C, acc[n][r], b2s);
    }
    // ---- half max (reduce over n, then c15 lanes) ----
    float M[4];
#pragma unroll
    for (int r = 0; r < 4; ++r) {
      float mm = acc[0][r];
#pragma unroll
      for (int n = 1; n < 8; ++n) mm = fmaxf(mm, acc[n][r]);
#pragma unroll
      for (int off = 1; off <= 8; off <<= 1) mm = fmaxf(mm, __shfl_xor(mm, off, 64));
      M[r] = mm;
    }
    if (h == 0) {
#pragma unroll
      for (int r = 0; r < 4; ++r) { m[r] = M[r]; sm[r] = 0.f; }
    } else {
#pragma unroll
      for (int r = 0; r < 4; ++r) {
        mOld[r] = m[r];                 // half-0 max (for stored-delta fixup)
        float mn = fmaxf(m[r], M[r]);
        sm[r] *= __expf(m[r] - mn);     // 1.0 when max unchanged
        m[r] = mn;                      // half-1 deltas are rel. to final max
      }
    }
    // ---- exp + per-lane sum + sparse APPEND (f16 delta, code) ----
#pragma unroll
    for (int n = 0; n < 8; ++n)
#pragma unroll
      for (int r = 0; r < 4; ++r) {
        float d = acc[n][r] - m[r];
        float e = __expf(d);
        sm[r] += e;
        if (e > TAU) {                          // near-one-hot: rare
          int p16 = wave * 16 + 4 * q + r;
          unsigned idx = atomicAdd(&sMem[WC + p16], 1u);
          if (idx < (unsigned)NSLOT) {
            unsigned db = (unsigned)__half_as_ushort(__float2half(d));
            sMem[WP + p16 * NSLOT + idx] =
                (db << 16) | (unsigned)(128 * h + 16 * n + c15);
          }
        }
      }
    if (h == 0) {
      asm volatile("s_waitcnt vmcnt(0)" ::: "memory");
      __syncthreads();  // bar3: half-1 B staged
    }
  }

  // ---- final denominator + invS + penalty (closed form from S only) ----
  float invS[4];
#pragma unroll
  for (int r = 0; r < 4; ++r) {
#pragma unroll
    for (int off = 1; off <= 8; off <<= 1) sm[r] += __shfl_xor(sm[r], off, 64);
    invS[r] = 1.0f / sm[r];
  }
  float pen = 0.f;
  if (c15 == 0) {
#pragma unroll
    for (int r = 0; r < 4; ++r)
      // sum_k min(w,1-w) = 1 + [w_max>1/2](1-2*w_max), w_max = invS exactly
      pen += (invS[r] > 0.5f) ? (2.0f - 2.0f * invS[r]) : 1.0f;
  }
  pen += __shfl_xor(pen, 16, 64);   // only lanes 0,16,32,48 are nonzero
  pen += __shfl_xor(pen, 32, 64);
  if (lane == 0) atomicAdd(penAcc, pen * INV_N);

  // ---- flush wave-local lists into each patch's OWN output region ----
  // (pairs rows 0-5, count row 6; K2 reads then overwrites. No barrier
  //  needed: lists are wave-local.)
  float* strip = out + (size_t)b * (512 * 512) + (size_t)(ht * 8) * 512;
#pragma unroll
  for (int pl = 0; pl < 16; ++pl) {
    int rI = pl & 3, qI = pl >> 2;
    float mo  = __shfl(mOld[rI], qI * 16, 64);
    float mf  = __shfl(m[rI],    qI * 16, 64);
    float isp = __shfl(invS[rI], qI * 16, 64);
    int p16 = wave * 16 + pl;
    unsigned cnt = sMem[WC + p16];
    cnt = cnt > (unsigned)NSLOT ? (unsigned)NSLOT : cnt;
    float* stash = strip + p16 * 8;
    if (lane == 0) *reinterpret_cast<unsigned*>(stash + 6 * 512) = cnt;
    if ((unsigned)lane < cnt) {
      unsigned pw = sMem[WP + p16 * NSLOT + lane];
      unsigned code = pw & 0xFFFFu;
      float delta = __half2float(__ushort_as_half((unsigned short)(pw >> 16)));
      float w = __expf(delta + (code < 128u ? mo - mf : 0.f)) * isp;
      *reinterpret_cast<uint2*>(stash + (lane >> 2) * 512 + (lane & 3) * 2) =
          make_uint2(__float_as_uint(w), code);
    }
  }
}

// K2: sparse reconstruct + fold. Per patch: <=24 broadcast (w, code) pairs
// read from the patch's own output region, rr[d=lane] = sum w * blk[c][d];
// then the float4 writeout overwrites the stash. Patches independent -> ILP.
__global__ __launch_bounds__(256, 8) void recon2(const float* __restrict__ blk,
                                                 float* __restrict__ out) {
  __shared__ float sMemF[64 * 68];

  const int tid = threadIdx.x;
  const int lane = tid & 63;
  const int wave = tid >> 6;
  const int b = blockIdx.x >> 6;
  const int ht = blockIdx.x & 63;

  float* strip = out + (size_t)b * (512 * 512) + (size_t)(ht * 8) * 512;
#pragma unroll
  for (int pl = 0; pl < 16; ++pl) {
    int p = wave * 16 + pl;
    const float* stash = strip + p * 8;
    unsigned cnt = *reinterpret_cast<const unsigned*>(stash + 6 * 512);
    cnt = cnt > (unsigned)NSLOT ? (unsigned)NSLOT : cnt;
    float rr = 0.f;
    for (unsigned i = 0; i < cnt; ++i) {  // avg ~1-3 iterations, uniform
      uint2 pr = *reinterpret_cast<const uint2*>(
          stash + (i >> 2) * 512 + (i & 3) * 2);            // broadcast
      rr = fmaf(__uint_as_float(pr.x),
                blk[(size_t)pr.y * 64 + lane], rr);         // coalesced, L2-hot
    }
    sMemF[p * 68 + lane] = rr;
  }
  // wave w owns cols [128w, 128w+128) of the 8x512 strip; same-wave LDS
  // RAW ordered by lgkmcnt; stores depend on loads via rr -> read-then-write.
  float* outBase = strip + wave * 128;
#pragma unroll
  for (int i = 0; i < 4; ++i) {
    int f = i * 64 + lane;          // float4-chunk id in wave's 8x128 stripe
    int row = f >> 5;               // 0..7
    int cc = f & 31;                // float4 col within stripe
    int wtl = cc >> 1, hw = cc & 1;
    float4 v = *reinterpret_cast<const float4*>(
        &sMemF[(wave * 16 + wtl) * 68 + row * 8 + hw * 4]);
    *reinterpret_cast<float4*>(outBase + row * 512 + cc * 4) = v;
  }
}

extern "C" void kernel_launch(void* const* d_in, const int* in_sizes, int n_in,
                              void* d_out, int out_size, void* d_ws, size_t ws_size,
                              hipStream_t stream) {
  const float* img = (const float*)d_in[0];   // (64,1,512,512) fp32
  const float* blk = (const float*)d_in[1];   // (256,8,8) fp32
  float* out = (float*)d_out;
  float* penSlot = out + IMG_ELEMS;

  unsigned* wsBh = (unsigned*)d_ws;           // 32 KB (pre-swizzled)
  unsigned* wsBl = wsBh + 8192;               // 32 KB (pre-swizzled)
  float* wsB2 = (float*)(wsBl + 8192);        // 1 KB (-BETA*||b||^2)

  pack_codes<<<dim3(8), dim3(256), 0, stream>>>(blk, wsBh, wsBl, wsB2);
  hipMemsetAsync(penSlot, 0, sizeof(float), stream);
  recon_kernel<<<dim3(4096), dim3(256), 0, stream>>>(img, wsBh, wsBl, wsB2,
                                                     out, penSlot);
  recon2<<<dim3(4096), dim3(256), 0, stream>>>(blk, out);
}